// Round 7
// baseline (1715.544 us; speedup 1.0000x reference)
//
#include <hip/hip_runtime.h>
#include <hip/hip_bf16.h>

#define IGNORE_INDEX (-100)

using f32x4  = __attribute__((ext_vector_type(4))) float;
using f32x16 = __attribute__((ext_vector_type(16))) float;
using bf16x8 = __attribute__((ext_vector_type(8))) short;

constexpr int BM = 256, BN = 256;
constexpr int MT = 8;      // m tiles (2048 / 256)
constexpr int NT = 500;    // n tiles (128000 / 256)
constexpr int SROWS = 2047;
constexpr int DDIM = 2048;

constexpr size_t WS_ACC_BYTES = 16384;
constexpr size_t WS_A_BYTES   = (size_t)2048 * 2048 * 2;
constexpr size_t WS_W_BYTES   = (size_t)128000 * 2048 * 2;
constexpr size_t WS_NEED      = WS_ACC_BYTES + WS_A_BYTES + WS_W_BYTES;

__device__ __forceinline__ unsigned cvt_pk_bf16(float lo, float hi) {
    unsigned r;
    asm("v_cvt_pk_bf16_f32 %0, %1, %2" : "=v"(r) : "v"(lo), "v"(hi));
    return r;
}

__device__ __forceinline__ void gload_lds16(const void* g, void* l) {
    __builtin_amdgcn_global_load_lds(
        (__attribute__((address_space(1))) void*)(g),
        (__attribute__((address_space(3))) void*)(l), 16, 0, 0);
}

// ---------------- prepass: fp32 -> bf16 (RNE) ----------------
__global__ __launch_bounds__(256)
void cvt_f32_bf16(const float* __restrict__ src, unsigned short* __restrict__ dst, size_t n8)
{
    size_t i = (size_t)blockIdx.x * 256 + threadIdx.x;
    const size_t stride = (size_t)gridDim.x * 256;
    for (; i < n8; i += stride) {
        const float4* s = (const float4*)(src + i * 8);
        float4 a = s[0], b = s[1];
        uint4 u;
        u.x = cvt_pk_bf16(a.x, a.y); u.y = cvt_pk_bf16(a.z, a.w);
        u.z = cvt_pk_bf16(b.x, b.y); u.w = cvt_pk_bf16(b.z, b.w);
        ((uint4*)dst)[i] = u;
    }
}

// ------- main fused GEMM + CE epilogue: 32x32x16 MFMA, R4 staging cadence -------
__global__ __launch_bounds__(512, 2)
void ce_gemm32(const unsigned short* __restrict__ Abf,
               const unsigned short* __restrict__ Wbf,
               const float* __restrict__ bias,
               const int* __restrict__ labels,
               float* __restrict__ sumexp,
               float* __restrict__ tgt)
{
    // 2 bufs x (A[256][64] + B[256][64]) bf16 = 128 KiB
    __shared__ __align__(16) unsigned short lds[2 * 32768];

    const int bid = blockIdx.x;
    const int L = (bid & 7) * (MT * NT / 8) + (bid >> 3);
    const int n_tile = L >> 3;
    const int m_tile = L & 7;
    const int m_base = m_tile * BM;
    const int n_base = n_tile * BN;

    const int T    = threadIdx.x;
    const int lane = T & 63;
    const int wave = T >> 6;
    const int wm = wave >> 2;   // 0..1
    const int wn = wave & 3;    // 0..3
    const int l31 = lane & 31;
    const int hi5 = lane >> 5;  // 0..1 (k-chunk group)
    const int l7  = lane & 7;

    // per-k-step chunk byte offsets (shorts): phys chunk = (2*ks + hi5) ^ (row&7), row&7 == l7
    int cho[4];
#pragma unroll
    for (int ks = 0; ks < 4; ++ks) cho[ks] = (((2 * ks + hi5) ^ l7) << 3);

    // staging: thread T fills phys slot (row = base + T>>3, chunk = T&7);
    // logical source chunk = (T&7) ^ ((T>>3)&7)  [involution]
    const int srow8 = T >> 3;
    const int sch   = (T & 7) ^ ((T >> 3) & 7);

    f32x16 acc[4][2];
#pragma unroll
    for (int i = 0; i < 4; ++i)
#pragma unroll
        for (int j = 0; j < 2; ++j)
#pragma unroll
            for (int r = 0; r < 16; ++r)
                acc[i][j][r] = 0.f;

    const unsigned short* Asrc = Abf + (size_t)(m_base + srow8) * DDIM + sch * 8;
    const unsigned short* Bsrc = Wbf + (size_t)(n_base + srow8) * DDIM + sch * 8;
    const int wbase = wave * 512;   // shorts

    // one half-tile = 2 gload_lds per wave (128 rows x 64 cols bf16)
    auto STAGE_A = [&](int kt, int h) {
        const int kc = kt * 64; const int b = (kt & 1) * 32768;
#pragma unroll
        for (int i = 0; i < 2; ++i) {
            const int blk = 2 * h + i;
            gload_lds16(Asrc + (size_t)blk * 64 * DDIM + kc, &lds[b + blk * 4096 + wbase]);
        }
    };
    auto STAGE_B = [&](int kt, int h) {
        const int kc = kt * 64; const int b = (kt & 1) * 32768;
#pragma unroll
        for (int i = 0; i < 2; ++i) {
            const int blk = 2 * h + i;
            gload_lds16(Bsrc + (size_t)blk * 64 * DDIM + kc, &lds[b + 16384 + blk * 4096 + wbase]);
        }
    };

    const int aro = wm * 128 + l31;
    const int bro = wn * 64 + l31;

    // PH: one phase = one k-step (K=16). 6 ds_read_b128 + 8 MFMA 32x32x16.
#define PH(KS, BB, STAGE_STMT, WAIT_STMT) { \
    const unsigned short* As_ = &lds[BB]; \
    const unsigned short* Bs_ = &lds[(BB) + 16384]; \
    bf16x8 afr0 = *(const bf16x8*)&As_[(aro      ) * 64 + cho[KS]]; \
    bf16x8 afr1 = *(const bf16x8*)&As_[(aro + 32 ) * 64 + cho[KS]]; \
    bf16x8 afr2 = *(const bf16x8*)&As_[(aro + 64 ) * 64 + cho[KS]]; \
    bf16x8 afr3 = *(const bf16x8*)&As_[(aro + 96 ) * 64 + cho[KS]]; \
    bf16x8 bfr0 = *(const bf16x8*)&Bs_[(bro      ) * 64 + cho[KS]]; \
    bf16x8 bfr1 = *(const bf16x8*)&Bs_[(bro + 32 ) * 64 + cho[KS]]; \
    STAGE_STMT; \
    asm volatile("s_barrier" ::: "memory"); \
    asm volatile("s_waitcnt lgkmcnt(0)" ::: "memory"); \
    __builtin_amdgcn_s_setprio(1); \
    acc[0][0] = __builtin_amdgcn_mfma_f32_32x32x16_bf16(afr0, bfr0, acc[0][0], 0, 0, 0); \
    acc[0][1] = __builtin_amdgcn_mfma_f32_32x32x16_bf16(afr0, bfr1, acc[0][1], 0, 0, 0); \
    acc[1][0] = __builtin_amdgcn_mfma_f32_32x32x16_bf16(afr1, bfr0, acc[1][0], 0, 0, 0); \
    acc[1][1] = __builtin_amdgcn_mfma_f32_32x32x16_bf16(afr1, bfr1, acc[1][1], 0, 0, 0); \
    acc[2][0] = __builtin_amdgcn_mfma_f32_32x32x16_bf16(afr2, bfr0, acc[2][0], 0, 0, 0); \
    acc[2][1] = __builtin_amdgcn_mfma_f32_32x32x16_bf16(afr2, bfr1, acc[2][1], 0, 0, 0); \
    acc[3][0] = __builtin_amdgcn_mfma_f32_32x32x16_bf16(afr3, bfr0, acc[3][0], 0, 0, 0); \
    acc[3][1] = __builtin_amdgcn_mfma_f32_32x32x16_bf16(afr3, bfr1, acc[3][1], 0, 0, 0); \
    __builtin_amdgcn_s_setprio(0); \
    WAIT_STMT; \
    asm volatile("s_barrier" ::: "memory"); \
}

    // ---- prologue: tile 0 (buf0) fully + B halves of tile 1 (buf1) ----
    STAGE_A(0, 0); STAGE_A(0, 1); STAGE_B(0, 0); STAGE_B(0, 1);   // 8 loads
    STAGE_B(1, 0); STAGE_B(1, 1);                                 // 4 loads
    asm volatile("s_waitcnt vmcnt(4)" ::: "memory");               // tile 0 landed
    asm volatile("s_barrier" ::: "memory");

    // ---- main loop: 16 iterations x 2 K-tiles x 4 phases (R4 cadence) ----
    for (int i = 0; i < 16; ++i) {
        const int t0 = 2 * i, t1 = 2 * i + 1;
        const bool st = (i < 15);
        // tile t0 in buf0 (base 0)
        PH(0, 0, { STAGE_A(t1, 0); }, {});
        PH(1, 0, { STAGE_A(t1, 1); }, {});
        PH(2, 0, { if (st) STAGE_B(t0 + 2, 0); }, {});
        PH(3, 0, { if (st) STAGE_B(t0 + 2, 1); },
                 { if (st) { asm volatile("s_waitcnt vmcnt(4)" ::: "memory"); }
                   else    { asm volatile("s_waitcnt vmcnt(0)" ::: "memory"); } });
        // tile t1 in buf1 (base 32768)
        PH(0, 32768, { if (st) STAGE_A(t0 + 2, 0); }, {});
        PH(1, 32768, { if (st) STAGE_A(t0 + 2, 1); }, {});
        PH(2, 32768, { if (st) STAGE_B(t1 + 2, 0); }, {});
        PH(3, 32768, { if (st) STAGE_B(t1 + 2, 1); },
                     { if (st) { asm volatile("s_waitcnt vmcnt(4)" ::: "memory"); } });
    }
#undef PH

    // ---- epilogue: bias + exp + half-wave row reduce + target gather ----
    // D layout (m74/m101): col = lane&31, row = (r&3) + 8*(r>>2) + 4*hi5
    const int grow = m_base + wm * 128;
    const int gcol = n_base + wn * 64 + l31;
    const float bz0 = bias[gcol];
    const float bz1 = bias[gcol + 32];
#pragma unroll
    for (int mb = 0; mb < 4; ++mb) {
        float rs[16];
        int   rg[16];
#pragma unroll
        for (int r = 0; r < 16; ++r) {
            const int rowg = grow + mb * 32 + (r & 3) + 8 * (r >> 2) + 4 * hi5;
            rg[r] = rowg;
            const int lbl = (rowg < SROWS) ? labels[rowg + 1] : -1;
            const float s0 = acc[mb][0][r] + bz0;
            const float s1 = acc[mb][1][r] + bz1;
            if (lbl == gcol)      atomicAdd(&tgt[rowg], s0);
            if (lbl == gcol + 32) atomicAdd(&tgt[rowg], s1);
            float a = __expf(s0) + __expf(s1);
#pragma unroll
            for (int off = 1; off < 32; off <<= 1)
                a += __shfl_xor(a, off);
            rs[r] = a;
        }
        if (l31 == 0) {
#pragma unroll
            for (int r = 0; r < 16; ++r)
                if (rg[r] < SROWS) atomicAdd(&sumexp[rg[r]], rs[r]);
        }
    }
}

// ---------------- fallback: fp32 in, reg-staged cvt (round-1 kernel) ----------------
__global__ __launch_bounds__(512, 2)
void ce_fused_gemm(const float* __restrict__ emb,
                   const float* __restrict__ W,
                   const float* __restrict__ bias,
                   const int* __restrict__ labels,
                   float* __restrict__ sumexp,
                   float* __restrict__ tgt)
{
    constexpr int BK = 64;
    constexpr int KT = 32;
    __shared__ __align__(16) unsigned short As[2][BM * BK];
    __shared__ __align__(16) unsigned short Bs[2][BN * BK];

    const int bid = blockIdx.x;
    const int L = (bid & 7) * (MT * NT / 8) + (bid >> 3);
    const int n_tile = L >> 3;
    const int m_tile = L & 7;
    const size_t m_base = (size_t)m_tile * BM;
    const size_t n_base = (size_t)n_tile * BN;

    const int tid  = threadIdx.x;
    const int lane = tid & 63;
    const int wave = tid >> 6;
    const int wm = wave >> 2;
    const int wn = wave & 3;
    const int q = lane & 15;
    const int g = lane >> 4;
    const int r0 = tid >> 3;
    const int kg = tid & 7;

    float4 stA[4][2], stB[4][2];
    f32x4 acc[8][4];
#pragma unroll
    for (int i = 0; i < 8; ++i)
#pragma unroll
        for (int j = 0; j < 4; ++j)
            acc[i][j] = (f32x4){0.f, 0.f, 0.f, 0.f};

    const float* Ab = emb + m_base * DDIM + (size_t)kg * 8;
    const float* Bb = W   + n_base * DDIM + (size_t)kg * 8;

#define STAGE_LOAD(kt_) { \
    const size_t ko = (size_t)(kt_) * BK; \
    _Pragma("unroll") \
    for (int p = 0; p < 4; ++p) { \
        const int row = r0 + p * 64; \
        const float4* pa = (const float4*)(Ab + (size_t)row * DDIM + ko); \
        stA[p][0] = pa[0]; stA[p][1] = pa[1]; \
        const float4* pb = (const float4*)(Bb + (size_t)row * DDIM + ko); \
        stB[p][0] = pb[0]; stB[p][1] = pb[1]; \
    } }

#define STAGE_WRITE(bf_) { \
    _Pragma("unroll") \
    for (int p = 0; p < 4; ++p) { \
        const int row = r0 + p * 64; \
        const int sw = (kg * 8) ^ ((row & 7) << 3); \
        uint4 ua; \
        ua.x = cvt_pk_bf16(stA[p][0].x, stA[p][0].y); \
        ua.y = cvt_pk_bf16(stA[p][0].z, stA[p][0].w); \
        ua.z = cvt_pk_bf16(stA[p][1].x, stA[p][1].y); \
        ua.w = cvt_pk_bf16(stA[p][1].z, stA[p][1].w); \
        *(uint4*)&As[bf_][row * BK + sw] = ua; \
        uint4 ub; \
        ub.x = cvt_pk_bf16(stB[p][0].x, stB[p][0].y); \
        ub.y = cvt_pk_bf16(stB[p][0].z, stB[p][0].w); \
        ub.z = cvt_pk_bf16(stB[p][1].x, stB[p][1].y); \
        ub.w = cvt_pk_bf16(stB[p][1].z, stB[p][1].w); \
        *(uint4*)&Bs[bf_][row * BK + sw] = ub; \
    } }

#define COMPUTE(bf_) { \
    _Pragma("unroll") \
    for (int kh = 0; kh < 2; ++kh) { \
        const int c = kh * 32 + g * 8; \
        bf16x8 bfr[4]; \
        _Pragma("unroll") \
        for (int nf = 0; nf < 4; ++nf) { \
            const int rr = wn * 64 + nf * 16 + q; \
            bfr[nf] = *(const bf16x8*)&Bs[bf_][rr * BK + (c ^ ((rr & 7) << 3))]; \
        } \
        _Pragma("unroll") \
        for (int mf = 0; mf < 8; ++mf) { \
            const int rr = wm * 128 + mf * 16 + q; \
            bf16x8 afr = *(const bf16x8*)&As[bf_][rr * BK + (c ^ ((rr & 7) << 3))]; \
            _Pragma("unroll") \
            for (int nf = 0; nf < 4; ++nf) \
                acc[mf][nf] = __builtin_amdgcn_mfma_f32_16x16x32_bf16(afr, bfr[nf], acc[mf][nf], 0, 0, 0); \
        } \
    } }

    STAGE_LOAD(0);
    STAGE_WRITE(0);
    __syncthreads();

    int buf = 0;
    for (int kt = 0; kt < KT; ++kt) {
        if (kt + 1 < KT) STAGE_LOAD(kt + 1);
        COMPUTE(buf);
        if (kt + 1 < KT) STAGE_WRITE(buf ^ 1);
        __syncthreads();
        buf ^= 1;
    }

    const int grow_base = (int)m_base + wm * 128;
    const int gcol_base = (int)n_base + wn * 64;
#pragma unroll
    for (int mf = 0; mf < 8; ++mf) {
        const int rb = grow_base + mf * 16 + g * 4;
        int lbl[4];
#pragma unroll
        for (int r = 0; r < 4; ++r)
            lbl[r] = (rb + r < SROWS) ? labels[rb + r + 1] : -1;
        float rsum[4] = {0.f, 0.f, 0.f, 0.f};
#pragma unroll
        for (int nf = 0; nf < 4; ++nf) {
            const int gc = gcol_base + nf * 16 + q;
            const float bz = bias[gc];
            const f32x4 v = acc[mf][nf];
#pragma unroll
            for (int r = 0; r < 4; ++r) {
                const float s = v[r] + bz;
                if (lbl[r] == gc) atomicAdd(&tgt[rb + r], s);
                rsum[r] += __expf(s);
            }
        }
#pragma unroll
        for (int r = 0; r < 4; ++r) {
#pragma unroll
            for (int off = 1; off < 16; off <<= 1)
                rsum[r] += __shfl_xor(rsum[r], off);
        }
        if (q == 0) {
#pragma unroll
            for (int r = 0; r < 4; ++r)
                if (rb + r < SROWS) atomicAdd(&sumexp[rb + r], rsum[r]);
        }
    }
#undef STAGE_LOAD
#undef STAGE_WRITE
#undef COMPUTE
}

__global__ void ce_finalize(const float* __restrict__ sumexp,
                            const float* __restrict__ tgt,
                            const int* __restrict__ labels,
                            float* __restrict__ out)
{
    const int tid = threadIdx.x;
    float acc = 0.f, cnt = 0.f;
    for (int s = tid; s < SROWS; s += 256) {
        if (labels[s + 1] != IGNORE_INDEX) {
            acc += __logf(sumexp[s]) - tgt[s];
            cnt += 1.f;
        }
    }
#pragma unroll
    for (int off = 32; off > 0; off >>= 1) {
        acc += __shfl_down(acc, off);
        cnt += __shfl_down(cnt, off);
    }
    __shared__ float sa[4], sc[4];
    if ((tid & 63) == 0) { sa[tid >> 6] = acc; sc[tid >> 6] = cnt; }
    __syncthreads();
    if (tid == 0) {
        float a = sa[0] + sa[1] + sa[2] + sa[3];
        float c = sc[0] + sc[1] + sc[2] + sc[3];
        out[0] = a / fmaxf(c, 1.f);
    }
}

extern "C" void kernel_launch(void* const* d_in, const int* in_sizes, int n_in,
                              void* d_out, int out_size, void* d_ws, size_t ws_size,
                              hipStream_t stream)
{
    const float* emb    = (const float*)d_in[1];
    const float* W      = (const float*)d_in[2];
    const float* bias   = (const float*)d_in[3];
    const int*   labels = (const int*)d_in[4];

    float* wsf    = (float*)d_ws;
    float* sumexp = wsf;
    float* tgt    = wsf + 2048;

    hipMemsetAsync(d_ws, 0, WS_ACC_BYTES, stream);

    if (ws_size >= WS_NEED) {
        unsigned short* Abf = (unsigned short*)((char*)d_ws + WS_ACC_BYTES);
        unsigned short* Wbf = (unsigned short*)((char*)d_ws + WS_ACC_BYTES + WS_A_BYTES);
        cvt_f32_bf16<<<dim3(2048), dim3(256), 0, stream>>>(W, Wbf, (size_t)128000 * 2048 / 8);
        cvt_f32_bf16<<<dim3(256),  dim3(256), 0, stream>>>(emb, Abf, (size_t)2048 * 2048 / 8);
        ce_gemm32<<<dim3(MT * NT), dim3(512), 0, stream>>>(Abf, Wbf, bias, labels, sumexp, tgt);
    } else {
        ce_fused_gemm<<<dim3(MT * NT), dim3(512), 0, stream>>>(emb, W, bias, labels, sumexp, tgt);
    }
    ce_finalize<<<dim3(1), dim3(256), 0, stream>>>(sumexp, tgt, labels, (float*)d_out);
}

// Round 8
// 1529.912 us; speedup vs baseline: 1.1213x; 1.1213x over previous
//
#include <hip/hip_runtime.h>
#include <hip/hip_bf16.h>

#define IGNORE_INDEX (-100)

using f32x4  = __attribute__((ext_vector_type(4))) float;
using bf16x8 = __attribute__((ext_vector_type(8))) short;

constexpr int BM = 256, BN = 256;
constexpr int MT = 8;      // fallback m tiles (2048 / 256)
constexpr int NT = 500;    // fallback n tiles (128000 / 256)
constexpr int SROWS = 2047;
constexpr int DDIM = 2048;

constexpr size_t WS_ACC_BYTES = 16384;
constexpr size_t WS_A_BYTES   = (size_t)2048 * 2048 * 2;
constexpr size_t WS_W_BYTES   = (size_t)128000 * 2048 * 2;
constexpr size_t WS_NEED      = WS_ACC_BYTES + WS_A_BYTES + WS_W_BYTES;

__device__ __forceinline__ unsigned cvt_pk_bf16(float lo, float hi) {
    unsigned r;
    asm("v_cvt_pk_bf16_f32 %0, %1, %2" : "=v"(r) : "v"(lo), "v"(hi));
    return r;
}

__device__ __forceinline__ void gload_lds16(const void* g, void* l) {
    __builtin_amdgcn_global_load_lds(
        (__attribute__((address_space(1))) void*)(g),
        (__attribute__((address_space(3))) void*)(l), 16, 0, 0);
}

// ---------------- prepass: fp32 -> bf16 (RNE) ----------------
__global__ __launch_bounds__(256)
void cvt_f32_bf16(const float* __restrict__ src, unsigned short* __restrict__ dst, size_t n8)
{
    size_t i = (size_t)blockIdx.x * 256 + threadIdx.x;
    const size_t stride = (size_t)gridDim.x * 256;
    for (; i < n8; i += stride) {
        const float4* s = (const float4*)(src + i * 8);
        float4 a = s[0], b = s[1];
        uint4 u;
        u.x = cvt_pk_bf16(a.x, a.y); u.y = cvt_pk_bf16(a.z, a.w);
        u.z = cvt_pk_bf16(b.x, b.y); u.w = cvt_pk_bf16(b.z, b.w);
        ((uint4*)dst)[i] = u;
    }
}

// ---- main fused GEMM + CE epilogue: 128x128 tile, 4 waves, 2 blocks/CU, R4 phase shape ----
__global__ __launch_bounds__(256, 2)
void ce_gemm128(const unsigned short* __restrict__ Abf,
                const unsigned short* __restrict__ Wbf,
                const float* __restrict__ bias,
                const int* __restrict__ labels,
                float* __restrict__ sumexp,
                float* __restrict__ tgt)
{
    // 2 bufs x (A[128][64] + B[128][64]) bf16 = 64 KiB -> 2 blocks/CU
    __shared__ __align__(16) unsigned short lds[2 * 16384];

    const int bid = blockIdx.x;                  // 16000 blocks, %8==0 -> bijective
    const int L = (bid & 7) * 2000 + (bid >> 3);
    const int n_tile = L >> 4;                   // 0..999 (16 consecutive L share n_tile)
    const int m_tile = L & 15;                   // 0..15
    const int m_base = m_tile * 128;
    const int n_base = n_tile * 128;

    const int T    = threadIdx.x;                // 0..255
    const int lane = T & 63;
    const int wave = T >> 6;                     // 0..3
    const int wm = wave >> 1;                    // 0..1
    const int wn = wave & 1;                     // 0..1
    const int q = lane & 15;
    const int g = lane >> 4;                     // 0..3
    // R4-proven slot addressing: 8 slots of 8 shorts, phys slot = group ^ (row&7), row&7 == q&7
    const int c0 = ((g    ) ^ (q & 7)) << 3;
    const int c1 = ((4 + g) ^ (q & 7)) << 3;

    // staging: thread T -> phys slot (row = sweep*32 + T>>3, chunk = T&7);
    // logical source chunk = (T&7) ^ ((T>>3)&7)  [involution]
    const int srow = T >> 3;                     // 0..31
    const int sch  = (T & 7) ^ ((T >> 3) & 7);
    const int w512 = wave * 512;                 // shorts (8 rows x 64)

    f32x4 acc[4][4];
#pragma unroll
    for (int i = 0; i < 4; ++i)
#pragma unroll
        for (int j = 0; j < 4; ++j)
            acc[i][j] = (f32x4){0.f, 0.f, 0.f, 0.f};

    const unsigned short* Asrc = Abf + (size_t)(m_base + srow) * DDIM + sch * 8;
    const unsigned short* Bsrc = Wbf + (size_t)(n_base + srow) * DDIM + sch * 8;

    // full K-tile stage: 4 A-sweeps + 4 B-sweeps (32 rows each), 8 gload_lds
    auto STAGE = [&](int kt) {
        const int b = (kt & 1) * 16384;
        const int kc = kt * 64;
#pragma unroll
        for (int j = 0; j < 4; ++j)
            gload_lds16(Asrc + (size_t)j * 32 * DDIM + kc, &lds[b + j * 2048 + w512]);
#pragma unroll
        for (int j = 0; j < 4; ++j)
            gload_lds16(Bsrc + (size_t)j * 32 * DDIM + kc, &lds[b + 8192 + j * 2048 + w512]);
    };

    const int arow = wm * 64 + q;
    const int brow = wn * 64 + q;

    // PH: one phase = one k-half. 8 ds_read_b128 + 16 MFMA 16x16x32.
#define PH(CC, BB, STAGE_STMT, WAIT_STMT) { \
    const unsigned short* As_ = &lds[BB]; \
    const unsigned short* Bs_ = &lds[(BB) + 8192]; \
    bf16x8 afr[4], bfr[4]; \
    _Pragma("unroll") \
    for (int nf = 0; nf < 4; ++nf) \
        bfr[nf] = *(const bf16x8*)&Bs_[(brow + nf * 16) * 64 + (CC)]; \
    _Pragma("unroll") \
    for (int mf = 0; mf < 4; ++mf) \
        afr[mf] = *(const bf16x8*)&As_[(arow + mf * 16) * 64 + (CC)]; \
    STAGE_STMT; \
    asm volatile("s_barrier" ::: "memory"); \
    asm volatile("s_waitcnt lgkmcnt(0)" ::: "memory"); \
    __builtin_amdgcn_s_setprio(1); \
    _Pragma("unroll") \
    for (int mf = 0; mf < 4; ++mf) \
        _Pragma("unroll") \
        for (int nf = 0; nf < 4; ++nf) \
            acc[mf][nf] = __builtin_amdgcn_mfma_f32_16x16x32_bf16(afr[mf], bfr[nf], acc[mf][nf], 0, 0, 0); \
    __builtin_amdgcn_s_setprio(0); \
    WAIT_STMT; \
    asm volatile("s_barrier" ::: "memory"); \
}

    // prologue
    STAGE(0);
    asm volatile("s_waitcnt vmcnt(0)" ::: "memory");
    asm volatile("s_barrier" ::: "memory");

    // main loop: 32 K-tiles x 2 phases; stage t+1 early (phase 0), wait late (phase 1)
    for (int t = 0; t < 32; ++t) {
        const int b = (t & 1) * 16384;
        const bool st = (t < 31);
        PH(c0, b, { if (st) STAGE(t + 1); }, {});
        PH(c1, b, {},
                  { if (st) { asm volatile("s_waitcnt vmcnt(0)" ::: "memory"); } });
    }
#undef PH

    // ---- epilogue: bias + exp + row-sum + target gather ----
    const int grow = m_base + wm * 64;
    const int gcol = n_base + wn * 64;
#pragma unroll
    for (int mf = 0; mf < 4; ++mf) {
        const int rb = grow + mf * 16 + g * 4;
        int lbl[4];
#pragma unroll
        for (int r = 0; r < 4; ++r)
            lbl[r] = (rb + r < SROWS) ? labels[rb + r + 1] : -1;
        float rsum[4] = {0.f, 0.f, 0.f, 0.f};
#pragma unroll
        for (int nf = 0; nf < 4; ++nf) {
            const int gc = gcol + nf * 16 + q;
            const float bz = bias[gc];
            const f32x4 v = acc[mf][nf];
#pragma unroll
            for (int r = 0; r < 4; ++r) {
                const float s = v[r] + bz;
                if (lbl[r] == gc) atomicAdd(&tgt[rb + r], s);
                rsum[r] += __expf(s);
            }
        }
#pragma unroll
        for (int r = 0; r < 4; ++r) {
#pragma unroll
            for (int off = 1; off < 16; off <<= 1)
                rsum[r] += __shfl_xor(rsum[r], off);
        }
        if (q == 0) {
#pragma unroll
            for (int r = 0; r < 4; ++r)
                if (rb + r < SROWS) atomicAdd(&sumexp[rb + r], rsum[r]);
        }
    }
}

// ---------------- fallback: fp32 in, reg-staged cvt (round-1 kernel) ----------------
__global__ __launch_bounds__(512, 2)
void ce_fused_gemm(const float* __restrict__ emb,
                   const float* __restrict__ W,
                   const float* __restrict__ bias,
                   const int* __restrict__ labels,
                   float* __restrict__ sumexp,
                   float* __restrict__ tgt)
{
    constexpr int BK = 64;
    constexpr int KT = 32;
    __shared__ __align__(16) unsigned short As[2][BM * BK];
    __shared__ __align__(16) unsigned short Bs[2][BN * BK];

    const int bid = blockIdx.x;
    const int L = (bid & 7) * (MT * NT / 8) + (bid >> 3);
    const int n_tile = L >> 3;
    const int m_tile = L & 7;
    const size_t m_base = (size_t)m_tile * BM;
    const size_t n_base = (size_t)n_tile * BN;

    const int tid  = threadIdx.x;
    const int lane = tid & 63;
    const int wave = tid >> 6;
    const int wm = wave >> 2;
    const int wn = wave & 3;
    const int q = lane & 15;
    const int g = lane >> 4;
    const int r0 = tid >> 3;
    const int kg = tid & 7;

    float4 stA[4][2], stB[4][2];
    f32x4 acc[8][4];
#pragma unroll
    for (int i = 0; i < 8; ++i)
#pragma unroll
        for (int j = 0; j < 4; ++j)
            acc[i][j] = (f32x4){0.f, 0.f, 0.f, 0.f};

    const float* Ab = emb + m_base * DDIM + (size_t)kg * 8;
    const float* Bb = W   + n_base * DDIM + (size_t)kg * 8;

#define STAGE_LOAD(kt_) { \
    const size_t ko = (size_t)(kt_) * BK; \
    _Pragma("unroll") \
    for (int p = 0; p < 4; ++p) { \
        const int row = r0 + p * 64; \
        const float4* pa = (const float4*)(Ab + (size_t)row * DDIM + ko); \
        stA[p][0] = pa[0]; stA[p][1] = pa[1]; \
        const float4* pb = (const float4*)(Bb + (size_t)row * DDIM + ko); \
        stB[p][0] = pb[0]; stB[p][1] = pb[1]; \
    } }

#define STAGE_WRITE(bf_) { \
    _Pragma("unroll") \
    for (int p = 0; p < 4; ++p) { \
        const int row = r0 + p * 64; \
        const int sw = (kg * 8) ^ ((row & 7) << 3); \
        uint4 ua; \
        ua.x = cvt_pk_bf16(stA[p][0].x, stA[p][0].y); \
        ua.y = cvt_pk_bf16(stA[p][0].z, stA[p][0].w); \
        ua.z = cvt_pk_bf16(stA[p][1].x, stA[p][1].y); \
        ua.w = cvt_pk_bf16(stA[p][1].z, stA[p][1].w); \
        *(uint4*)&As[bf_][row * BK + sw] = ua; \
        uint4 ub; \
        ub.x = cvt_pk_bf16(stB[p][0].x, stB[p][0].y); \
        ub.y = cvt_pk_bf16(stB[p][0].z, stB[p][0].w); \
        ub.z = cvt_pk_bf16(stB[p][1].x, stB[p][1].y); \
        ub.w = cvt_pk_bf16(stB[p][1].z, stB[p][1].w); \
        *(uint4*)&Bs[bf_][row * BK + sw] = ub; \
    } }

#define COMPUTE(bf_) { \
    _Pragma("unroll") \
    for (int kh = 0; kh < 2; ++kh) { \
        const int c = kh * 32 + g * 8; \
        bf16x8 bfr[4]; \
        _Pragma("unroll") \
        for (int nf = 0; nf < 4; ++nf) { \
            const int rr = wn * 64 + nf * 16 + q; \
            bfr[nf] = *(const bf16x8*)&Bs[bf_][rr * BK + (c ^ ((rr & 7) << 3))]; \
        } \
        _Pragma("unroll") \
        for (int mf = 0; mf < 8; ++mf) { \
            const int rr = wm * 128 + mf * 16 + q; \
            bf16x8 afr = *(const bf16x8*)&As[bf_][rr * BK + (c ^ ((rr & 7) << 3))]; \
            _Pragma("unroll") \
            for (int nf = 0; nf < 4; ++nf) \
                acc[mf][nf] = __builtin_amdgcn_mfma_f32_16x16x32_bf16(afr, bfr[nf], acc[mf][nf], 0, 0, 0); \
        } \
    } }

    STAGE_LOAD(0);
    STAGE_WRITE(0);
    __syncthreads();

    int buf = 0;
    for (int kt = 0; kt < KT; ++kt) {
        if (kt + 1 < KT) STAGE_LOAD(kt + 1);
        COMPUTE(buf);
        if (kt + 1 < KT) STAGE_WRITE(buf ^ 1);
        __syncthreads();
        buf ^= 1;
    }

    const int grow_base = (int)m_base + wm * 128;
    const int gcol_base = (int)n_base + wn * 64;
#pragma unroll
    for (int mf = 0; mf < 8; ++mf) {
        const int rb = grow_base + mf * 16 + g * 4;
        int lbl[4];
#pragma unroll
        for (int r = 0; r < 4; ++r)
            lbl[r] = (rb + r < SROWS) ? labels[rb + r + 1] : -1;
        float rsum[4] = {0.f, 0.f, 0.f, 0.f};
#pragma unroll
        for (int nf = 0; nf < 4; ++nf) {
            const int gc = gcol_base + nf * 16 + q;
            const float bz = bias[gc];
            const f32x4 v = acc[mf][nf];
#pragma unroll
            for (int r = 0; r < 4; ++r) {
                const float s = v[r] + bz;
                if (lbl[r] == gc) atomicAdd(&tgt[rb + r], s);
                rsum[r] += __expf(s);
            }
        }
#pragma unroll
        for (int r = 0; r < 4; ++r) {
#pragma unroll
            for (int off = 1; off < 16; off <<= 1)
                rsum[r] += __shfl_xor(rsum[r], off);
        }
        if (q == 0) {
#pragma unroll
            for (int r = 0; r < 4; ++r)
                if (rb + r < SROWS) atomicAdd(&sumexp[rb + r], rsum[r]);
        }
    }
#undef STAGE_LOAD
#undef STAGE_WRITE
#undef COMPUTE
}

__global__ void ce_finalize(const float* __restrict__ sumexp,
                            const float* __restrict__ tgt,
                            const int* __restrict__ labels,
                            float* __restrict__ out)
{
    const int tid = threadIdx.x;
    float acc = 0.f, cnt = 0.f;
    for (int s = tid; s < SROWS; s += 256) {
        if (labels[s + 1] != IGNORE_INDEX) {
            acc += __logf(sumexp[s]) - tgt[s];
            cnt += 1.f;
        }
    }
#pragma unroll
    for (int off = 32; off > 0; off >>= 1) {
        acc += __shfl_down(acc, off);
        cnt += __shfl_down(cnt, off);
    }
    __shared__ float sa[4], sc[4];
    if ((tid & 63) == 0) { sa[tid >> 6] = acc; sc[tid >> 6] = cnt; }
    __syncthreads();
    if (tid == 0) {
        float a = sa[0] + sa[1] + sa[2] + sa[3];
        float c = sc[0] + sc[1] + sc[2] + sc[3];
        out[0] = a / fmaxf(c, 1.f);
    }
}

extern "C" void kernel_launch(void* const* d_in, const int* in_sizes, int n_in,
                              void* d_out, int out_size, void* d_ws, size_t ws_size,
                              hipStream_t stream)
{
    const float* emb    = (const float*)d_in[1];
    const float* W      = (const float*)d_in[2];
    const float* bias   = (const float*)d_in[3];
    const int*   labels = (const int*)d_in[4];

    float* wsf    = (float*)d_ws;
    float* sumexp = wsf;
    float* tgt    = wsf + 2048;

    hipMemsetAsync(d_ws, 0, WS_ACC_BYTES, stream);

    if (ws_size >= WS_NEED) {
        unsigned short* Abf = (unsigned short*)((char*)d_ws + WS_ACC_BYTES);
        unsigned short* Wbf = (unsigned short*)((char*)d_ws + WS_ACC_BYTES + WS_A_BYTES);
        cvt_f32_bf16<<<dim3(2048), dim3(256), 0, stream>>>(W, Wbf, (size_t)128000 * 2048 / 8);
        cvt_f32_bf16<<<dim3(256),  dim3(256), 0, stream>>>(emb, Abf, (size_t)2048 * 2048 / 8);
        ce_gemm128<<<dim3(16000), dim3(256), 0, stream>>>(Abf, Wbf, bias, labels, sumexp, tgt);
    } else {
        ce_fused_gemm<<<dim3(MT * NT), dim3(512), 0, stream>>>(emb, W, bias, labels, sumexp, tgt);
    }
    ce_finalize<<<dim3(1), dim3(256), 0, stream>>>(sumexp, tgt, labels, (float*)d_out);
}

// Round 9
// 1297.175 us; speedup vs baseline: 1.3225x; 1.1794x over previous
//
#include <hip/hip_runtime.h>
#include <hip/hip_bf16.h>

#define IGNORE_INDEX (-100)

using f32x4  = __attribute__((ext_vector_type(4))) float;
using bf16x8 = __attribute__((ext_vector_type(8))) short;
using i32x8  = __attribute__((ext_vector_type(8))) int;

constexpr int BM = 256, BN = 256;
constexpr int MT = 8;      // m tiles (2048 / 256)
constexpr int NT = 500;    // n tiles (128000 / 256)
constexpr int SROWS = 2047;
constexpr int DDIM = 2048;

// fp8 workspace layout
constexpr size_t WS_ACC_BYTES = 16384;
constexpr size_t WS_A8_BYTES  = (size_t)2048 * 2048;
constexpr size_t WS_W8_BYTES  = (size_t)128000 * 2048;
constexpr size_t WS_NEED8     = WS_ACC_BYTES + WS_A8_BYTES + WS_W8_BYTES;

#define SCL8 0x7F7F7F7F   // E8M0 = 127 -> 2^0 = 1.0 in all four bytes

__device__ __forceinline__ unsigned cvt_pk_bf16(float lo, float hi) {
    unsigned r;
    asm("v_cvt_pk_bf16_f32 %0, %1, %2" : "=v"(r) : "v"(lo), "v"(hi));
    return r;
}

__device__ __forceinline__ void gload_lds16(const void* g, void* l) {
    __builtin_amdgcn_global_load_lds(
        (__attribute__((address_space(1))) void*)(g),
        (__attribute__((address_space(3))) void*)(l), 16, 0, 0);
}

// ---------------- prepass: fp32 -> fp8 e4m3 (HW cvt, 4 floats/thread) ----------------
__global__ __launch_bounds__(256)
void cvt_f32_fp8(const float* __restrict__ src, unsigned* __restrict__ dst, size_t n4)
{
    size_t i = (size_t)blockIdx.x * 256 + threadIdx.x;
    const size_t stride = (size_t)gridDim.x * 256;
    for (; i < n4; i += stride) {
        const float4 v = ((const float4*)src)[i];
        unsigned u = __builtin_amdgcn_cvt_pk_fp8_f32(v.x, v.y, 0, false);
        u = __builtin_amdgcn_cvt_pk_fp8_f32(v.z, v.w, u, true);
        dst[i] = u;
    }
}

// ------- main fused GEMM + CE epilogue: MX-fp8 K=128, R4 structure verbatim -------
__global__ __launch_bounds__(512, 2)
void ce_gemmf8(const unsigned char* __restrict__ Af8,
               const unsigned char* __restrict__ Wf8,
               const float* __restrict__ bias,
               const int* __restrict__ labels,
               float* __restrict__ sumexp,
               float* __restrict__ tgt)
{
    // 2 bufs x (A[256][128B] + B[256][128B]) = 128 KiB
    __shared__ __align__(16) unsigned char lds[2 * 65536];

    const int bid = blockIdx.x;
    const int L = (bid & 7) * (MT * NT / 8) + (bid >> 3);
    const int n_tile = L >> 3;
    const int m_tile = L & 7;
    const int m_base = m_tile * BM;
    const int n_base = n_tile * BN;

    const int T    = threadIdx.x;
    const int lane = T & 63;
    const int wave = T >> 6;
    const int wm = wave >> 2;   // 0..1
    const int wn = wave & 3;    // 0..3
    const int q = lane & 15;
    const int g = lane >> 4;    // 0..3
    const int q7 = q & 7;
    // lane's 32 K-bytes = logical 16B-chunks {2g, 2g+1}; phys = logical ^ (row&7), row&7 == q7
    const int cLo = (((2 * g)     ^ q7) << 4);
    const int cHi = (((2 * g + 1) ^ q7) << 4);

    // staging: thread T -> phys slot (row = T>>3, chunk = T&7); logical = (T&7)^((T>>3)&7)
    const int srow8 = T >> 3;
    const int sch   = (T & 7) ^ ((T >> 3) & 7);

    f32x4 acc[8][4];
#pragma unroll
    for (int i = 0; i < 8; ++i)
#pragma unroll
        for (int j = 0; j < 4; ++j)
            acc[i][j] = (f32x4){0.f, 0.f, 0.f, 0.f};

    const unsigned char* Asrc = Af8 + (size_t)(m_base + srow8) * DDIM + sch * 16;
    const unsigned char* Bsrc = Wf8 + (size_t)(n_base + srow8) * DDIM + sch * 16;
    const int wbyte = wave * 1024;

    // one half-tile = 2 gload_lds per wave (128 rows x 128 B)
    auto STAGE_A = [&](int kt, int h) {
        const int kc = kt * 128; const int b = (kt & 1) * 65536;
#pragma unroll
        for (int i = 0; i < 2; ++i) {
            const int blk = 2 * h + i;
            gload_lds16(Asrc + (size_t)blk * 64 * DDIM + kc, &lds[b + blk * 8192 + wbyte]);
        }
    };
    auto STAGE_B = [&](int kt, int h) {
        const int kc = kt * 128; const int b = (kt & 1) * 65536;
#pragma unroll
        for (int i = 0; i < 2; ++i) {
            const int blk = 2 * h + i;
            gload_lds16(Bsrc + (size_t)blk * 64 * DDIM + kc, &lds[b + 32768 + blk * 8192 + wbyte]);
        }
    };

    const int arow = wm * 128 + q;
    const int brow = wn * 64 + q;
    i32x8 bfr[4];   // B frags of current K-tile (read at phase j==0, live 4 phases)

#define RD_FRAG(dst_, baseb_) { \
    const uint4 lo_ = *(const uint4*)&lds[(baseb_) + cLo]; \
    const uint4 hi_ = *(const uint4*)&lds[(baseb_) + cHi]; \
    dst_[0] = lo_.x; dst_[1] = lo_.y; dst_[2] = lo_.z; dst_[3] = lo_.w; \
    dst_[4] = hi_.x; dst_[5] = hi_.y; dst_[6] = hi_.z; dst_[7] = hi_.w; \
}

    // PH: one phase = mf rows {2j, 2j+1}, full K=128. 4(+8) ds_read_b128 + 8 MFMA.
#define PH(j, BB, STAGE_STMT, WAIT_STMT) { \
    i32x8 a0, a1; \
    RD_FRAG(a0, (BB) + (arow + (2*(j)    ) * 16) * 128); \
    RD_FRAG(a1, (BB) + (arow + (2*(j) + 1) * 16) * 128); \
    if ((j) == 0) { \
        _Pragma("unroll") \
        for (int nf = 0; nf < 4; ++nf) \
            RD_FRAG(bfr[nf], (BB) + 32768 + (brow + nf * 16) * 128); \
    } \
    STAGE_STMT; \
    if ((j) == 0) asm volatile("s_waitcnt lgkmcnt(8)" ::: "memory"); \
    asm volatile("s_barrier" ::: "memory"); \
    asm volatile("s_waitcnt lgkmcnt(0)" ::: "memory"); \
    __builtin_amdgcn_s_setprio(1); \
    _Pragma("unroll") \
    for (int nf = 0; nf < 4; ++nf) \
        acc[2*(j)][nf] = __builtin_amdgcn_mfma_scale_f32_16x16x128_f8f6f4( \
            a0, bfr[nf], acc[2*(j)][nf], 0, 0, 0, SCL8, 0, SCL8); \
    _Pragma("unroll") \
    for (int nf = 0; nf < 4; ++nf) \
        acc[2*(j)+1][nf] = __builtin_amdgcn_mfma_scale_f32_16x16x128_f8f6f4( \
            a1, bfr[nf], acc[2*(j)+1][nf], 0, 0, 0, SCL8, 0, SCL8); \
    __builtin_amdgcn_s_setprio(0); \
    WAIT_STMT; \
    asm volatile("s_barrier" ::: "memory"); \
}

    // ---- prologue: tile 0 (buf0) fully + B halves of tile 1 (buf1) ----
    STAGE_A(0, 0); STAGE_A(0, 1); STAGE_B(0, 0); STAGE_B(0, 1);   // 8 loads
    STAGE_B(1, 0); STAGE_B(1, 1);                                 // 4 loads
    asm volatile("s_waitcnt vmcnt(4)" ::: "memory");               // tile 0 landed
    asm volatile("s_barrier" ::: "memory");

    // ---- main loop: 8 iterations x 2 K-tiles (K=128 each) x 4 phases (R4 cadence) ----
    for (int i = 0; i < 8; ++i) {
        const int t0 = 2 * i, t1 = 2 * i + 1;
        const bool st = (i < 7);
        // tile t0 in buf0
        PH(0, 0, { STAGE_A(t1, 0); }, {});
        PH(1, 0, { STAGE_A(t1, 1); }, {});
        PH(2, 0, { if (st) STAGE_B(t0 + 2, 0); }, {});
        PH(3, 0, { if (st) STAGE_B(t0 + 2, 1); },
                 { if (st) { asm volatile("s_waitcnt vmcnt(4)" ::: "memory"); }
                   else    { asm volatile("s_waitcnt vmcnt(0)" ::: "memory"); } });
        // tile t1 in buf1
        PH(0, 65536, { if (st) STAGE_A(t0 + 2, 0); }, {});
        PH(1, 65536, { if (st) STAGE_A(t0 + 2, 1); }, {});
        PH(2, 65536, { if (st) STAGE_B(t1 + 2, 0); }, {});
        PH(3, 65536, { if (st) STAGE_B(t1 + 2, 1); },
                     { if (st) { asm volatile("s_waitcnt vmcnt(4)" ::: "memory"); } });
    }
#undef PH
#undef RD_FRAG

    // ---- epilogue: bias + exp + row-sum + target gather (16x16 C/D layout) ----
    const int grow_base = m_base + wm * 128;
    const int gcol_base = n_base + wn * 64;
#pragma unroll
    for (int mf = 0; mf < 8; ++mf) {
        const int rb = grow_base + mf * 16 + g * 4;
        int lbl[4];
#pragma unroll
        for (int r = 0; r < 4; ++r)
            lbl[r] = (rb + r < SROWS) ? labels[rb + r + 1] : -1;
        float rsum[4] = {0.f, 0.f, 0.f, 0.f};
#pragma unroll
        for (int nf = 0; nf < 4; ++nf) {
            const int gc = gcol_base + nf * 16 + q;
            const float bz = bias[gc];
            const f32x4 v = acc[mf][nf];
#pragma unroll
            for (int r = 0; r < 4; ++r) {
                const float s = v[r] + bz;
                if (lbl[r] == gc) atomicAdd(&tgt[rb + r], s);
                rsum[r] += __expf(s);
            }
        }
#pragma unroll
        for (int r = 0; r < 4; ++r) {
#pragma unroll
            for (int off = 1; off < 16; off <<= 1)
                rsum[r] += __shfl_xor(rsum[r], off);
        }
        if (q == 0) {
#pragma unroll
            for (int r = 0; r < 4; ++r)
                if (rb + r < SROWS) atomicAdd(&sumexp[rb + r], rsum[r]);
        }
    }
}

// ---------------- fallback: fp32 in, reg-staged cvt to bf16 (round-1 kernel) ----------------
__global__ __launch_bounds__(512, 2)
void ce_fused_gemm(const float* __restrict__ emb,
                   const float* __restrict__ W,
                   const float* __restrict__ bias,
                   const int* __restrict__ labels,
                   float* __restrict__ sumexp,
                   float* __restrict__ tgt)
{
    constexpr int BK = 64;
    constexpr int KT = 32;
    __shared__ __align__(16) unsigned short As[2][BM * BK];
    __shared__ __align__(16) unsigned short Bs[2][BN * BK];

    const int bid = blockIdx.x;
    const int L = (bid & 7) * (MT * NT / 8) + (bid >> 3);
    const int n_tile = L >> 3;
    const int m_tile = L & 7;
    const size_t m_base = (size_t)m_tile * BM;
    const size_t n_base = (size_t)n_tile * BN;

    const int tid  = threadIdx.x;
    const int lane = tid & 63;
    const int wave = tid >> 6;
    const int wm = wave >> 2;
    const int wn = wave & 3;
    const int q = lane & 15;
    const int g = lane >> 4;
    const int r0 = tid >> 3;
    const int kg = tid & 7;

    float4 stA[4][2], stB[4][2];
    f32x4 acc[8][4];
#pragma unroll
    for (int i = 0; i < 8; ++i)
#pragma unroll
        for (int j = 0; j < 4; ++j)
            acc[i][j] = (f32x4){0.f, 0.f, 0.f, 0.f};

    const float* Ab = emb + m_base * DDIM + (size_t)kg * 8;
    const float* Bb = W   + n_base * DDIM + (size_t)kg * 8;

#define STAGE_LOAD(kt_) { \
    const size_t ko = (size_t)(kt_) * BK; \
    _Pragma("unroll") \
    for (int p = 0; p < 4; ++p) { \
        const int row = r0 + p * 64; \
        const float4* pa = (const float4*)(Ab + (size_t)row * DDIM + ko); \
        stA[p][0] = pa[0]; stA[p][1] = pa[1]; \
        const float4* pb = (const float4*)(Bb + (size_t)row * DDIM + ko); \
        stB[p][0] = pb[0]; stB[p][1] = pb[1]; \
    } }

#define STAGE_WRITE(bf_) { \
    _Pragma("unroll") \
    for (int p = 0; p < 4; ++p) { \
        const int row = r0 + p * 64; \
        const int sw = (kg * 8) ^ ((row & 7) << 3); \
        uint4 ua; \
        ua.x = cvt_pk_bf16(stA[p][0].x, stA[p][0].y); \
        ua.y = cvt_pk_bf16(stA[p][0].z, stA[p][0].w); \
        ua.z = cvt_pk_bf16(stA[p][1].x, stA[p][1].y); \
        ua.w = cvt_pk_bf16(stA[p][1].z, stA[p][1].w); \
        *(uint4*)&As[bf_][row * BK + sw] = ua; \
        uint4 ub; \
        ub.x = cvt_pk_bf16(stB[p][0].x, stB[p][0].y); \
        ub.y = cvt_pk_bf16(stB[p][0].z, stB[p][0].w); \
        ub.z = cvt_pk_bf16(stB[p][1].x, stB[p][1].y); \
        ub.w = cvt_pk_bf16(stB[p][1].z, stB[p][1].w); \
        *(uint4*)&Bs[bf_][row * BK + sw] = ub; \
    } }

#define COMPUTE(bf_) { \
    _Pragma("unroll") \
    for (int kh = 0; kh < 2; ++kh) { \
        const int c = kh * 32 + g * 8; \
        bf16x8 bfr[4]; \
        _Pragma("unroll") \
        for (int nf = 0; nf < 4; ++nf) { \
            const int rr = wn * 64 + nf * 16 + q; \
            bfr[nf] = *(const bf16x8*)&Bs[bf_][rr * BK + (c ^ ((rr & 7) << 3))]; \
        } \
        _Pragma("unroll") \
        for (int mf = 0; mf < 8; ++mf) { \
            const int rr = wm * 128 + mf * 16 + q; \
            bf16x8 afr = *(const bf16x8*)&As[bf_][rr * BK + (c ^ ((rr & 7) << 3))]; \
            _Pragma("unroll") \
            for (int nf = 0; nf < 4; ++nf) \
                acc[mf][nf] = __builtin_amdgcn_mfma_f32_16x16x32_bf16(afr, bfr[nf], acc[mf][nf], 0, 0, 0); \
        } \
    } }

    STAGE_LOAD(0);
    STAGE_WRITE(0);
    __syncthreads();

    int buf = 0;
    for (int kt = 0; kt < KT; ++kt) {
        if (kt + 1 < KT) STAGE_LOAD(kt + 1);
        COMPUTE(buf);
        if (kt + 1 < KT) STAGE_WRITE(buf ^ 1);
        __syncthreads();
        buf ^= 1;
    }

    const int grow_base = (int)m_base + wm * 128;
    const int gcol_base = (int)n_base + wn * 64;
#pragma unroll
    for (int mf = 0; mf < 8; ++mf) {
        const int rb = grow_base + mf * 16 + g * 4;
        int lbl[4];
#pragma unroll
        for (int r = 0; r < 4; ++r)
            lbl[r] = (rb + r < SROWS) ? labels[rb + r + 1] : -1;
        float rsum[4] = {0.f, 0.f, 0.f, 0.f};
#pragma unroll
        for (int nf = 0; nf < 4; ++nf) {
            const int gc = gcol_base + nf * 16 + q;
            const float bz = bias[gc];
            const f32x4 v = acc[mf][nf];
#pragma unroll
            for (int r = 0; r < 4; ++r) {
                const float s = v[r] + bz;
                if (lbl[r] == gc) atomicAdd(&tgt[rb + r], s);
                rsum[r] += __expf(s);
            }
        }
#pragma unroll
        for (int r = 0; r < 4; ++r) {
#pragma unroll
            for (int off = 1; off < 16; off <<= 1)
                rsum[r] += __shfl_xor(rsum[r], off);
        }
        if (q == 0) {
#pragma unroll
            for (int r = 0; r < 4; ++r)
                if (rb + r < SROWS) atomicAdd(&sumexp[rb + r], rsum[r]);
        }
    }
#undef STAGE_LOAD
#undef STAGE_WRITE
#undef COMPUTE
}

__global__ void ce_finalize(const float* __restrict__ sumexp,
                            const float* __restrict__ tgt,
                            const int* __restrict__ labels,
                            float* __restrict__ out)
{
    const int tid = threadIdx.x;
    float acc = 0.f, cnt = 0.f;
    for (int s = tid; s < SROWS; s += 256) {
        if (labels[s + 1] != IGNORE_INDEX) {
            acc += __logf(sumexp[s]) - tgt[s];
            cnt += 1.f;
        }
    }
#pragma unroll
    for (int off = 32; off > 0; off >>= 1) {
        acc += __shfl_down(acc, off);
        cnt += __shfl_down(cnt, off);
    }
    __shared__ float sa[4], sc[4];
    if ((tid & 63) == 0) { sa[tid >> 6] = acc; sc[tid >> 6] = cnt; }
    __syncthreads();
    if (tid == 0) {
        float a = sa[0] + sa[1] + sa[2] + sa[3];
        float c = sc[0] + sc[1] + sc[2] + sc[3];
        out[0] = a / fmaxf(c, 1.f);
    }
}

extern "C" void kernel_launch(void* const* d_in, const int* in_sizes, int n_in,
                              void* d_out, int out_size, void* d_ws, size_t ws_size,
                              hipStream_t stream)
{
    const float* emb    = (const float*)d_in[1];
    const float* W      = (const float*)d_in[2];
    const float* bias   = (const float*)d_in[3];
    const int*   labels = (const int*)d_in[4];

    float* wsf    = (float*)d_ws;
    float* sumexp = wsf;
    float* tgt    = wsf + 2048;

    hipMemsetAsync(d_ws, 0, WS_ACC_BYTES, stream);

    if (ws_size >= WS_NEED8) {
        unsigned char* Af8 = (unsigned char*)d_ws + WS_ACC_BYTES;
        unsigned char* Wf8 = (unsigned char*)d_ws + WS_ACC_BYTES + WS_A8_BYTES;
        cvt_f32_fp8<<<dim3(4096), dim3(256), 0, stream>>>(W, (unsigned*)Wf8, (size_t)128000 * 2048 / 4);
        cvt_f32_fp8<<<dim3(512),  dim3(256), 0, stream>>>(emb, (unsigned*)Af8, (size_t)2048 * 2048 / 4);
        ce_gemmf8<<<dim3(MT * NT), dim3(512), 0, stream>>>(Af8, Wf8, bias, labels, sumexp, tgt);
    } else {
        ce_fused_gemm<<<dim3(MT * NT), dim3(512), 0, stream>>>(emb, W, bias, labels, sumexp, tgt);
    }
    ce_finalize<<<dim3(1), dim3(256), 0, stream>>>(sumexp, tgt, labels, (float*)d_out);
}

// Round 10
// 1200.922 us; speedup vs baseline: 1.4285x; 1.0801x over previous
//
#include <hip/hip_runtime.h>
#include <hip/hip_bf16.h>

#define IGNORE_INDEX (-100)

using f32x4  = __attribute__((ext_vector_type(4))) float;
using bf16x8 = __attribute__((ext_vector_type(8))) short;
using i32x8  = __attribute__((ext_vector_type(8))) int;

constexpr int BM = 256, BN = 256;
constexpr int MT = 8;      // m tiles (2048 / 256)
constexpr int NT = 500;    // fallback n tiles (128000 / 256)
constexpr int SROWS = 2047;
constexpr int DDIM = 2048;

// fp8 workspace layout
constexpr size_t WS_ACC_BYTES = 16384;
constexpr size_t WS_A8_BYTES  = (size_t)2048 * 2048;
constexpr size_t WS_W8_BYTES  = (size_t)128000 * 2048;
constexpr size_t WS_NEED8     = WS_ACC_BYTES + WS_A8_BYTES + WS_W8_BYTES;

#define SCL8 0x7F7F7F7F   // E8M0 = 127 -> 2^0 = 1.0 in all four bytes

__device__ __forceinline__ unsigned cvt_pk_bf16(float lo, float hi) {
    unsigned r;
    asm("v_cvt_pk_bf16_f32 %0, %1, %2" : "=v"(r) : "v"(lo), "v"(hi));
    return r;
}

__device__ __forceinline__ void gload_lds16(const void* g, void* l) {
    __builtin_amdgcn_global_load_lds(
        (__attribute__((address_space(1))) void*)(g),
        (__attribute__((address_space(3))) void*)(l), 16, 0, 0);
}

// ---------------- prepass: fp32 -> fp8 e4m3 (HW cvt, 4 floats/thread) ----------------
__global__ __launch_bounds__(256)
void cvt_f32_fp8(const float* __restrict__ src, unsigned* __restrict__ dst, size_t n4)
{
    size_t i = (size_t)blockIdx.x * 256 + threadIdx.x;
    const size_t stride = (size_t)gridDim.x * 256;
    for (; i < n4; i += stride) {
        const float4 v = ((const float4*)src)[i];
        unsigned u = __builtin_amdgcn_cvt_pk_fp8_f32(v.x, v.y, 0, false);
        u = __builtin_amdgcn_cvt_pk_fp8_f32(v.z, v.w, u, true);
        dst[i] = u;
    }
}

// ---- main fused GEMM + CE: MX-fp8 K=128, 256x128 tile, 64x64 wave tile (64 AGPR acc) ----
__global__ __launch_bounds__(512, 2)
void ce_gemmf8b(const unsigned char* __restrict__ Af8,
                const unsigned char* __restrict__ Wf8,
                const float* __restrict__ bias,
                const int* __restrict__ labels,
                float* __restrict__ sumexp,
                float* __restrict__ tgt)
{
    // 2 bufs x (A[256][128B] = 32KB + B[128][128B] = 16KB) = 96 KiB
    __shared__ __align__(16) unsigned char lds[2 * 49152];

    const int bid = blockIdx.x;                  // 8000 blocks, %8==0 -> bijective
    const int L = (bid & 7) * 1000 + (bid >> 3);
    const int n_tile = L >> 3;                   // 0..999
    const int m_tile = L & 7;                    // 0..7
    const int m_base = m_tile * BM;
    const int n_base = n_tile * 128;

    const int T    = threadIdx.x;
    const int lane = T & 63;
    const int wave = T >> 6;
    const int wm = wave >> 1;   // 0..3 (64-row group)
    const int wn = wave & 1;    // 0..1 (64-col group)
    const int q = lane & 15;
    const int g = lane >> 4;    // 0..3
    const int q7 = q & 7;
    // lane's 32 K-bytes = logical 16B-chunks {2g, 2g+1}; phys = logical ^ (row&7), row&7 == q7
    const int cLo = (((2 * g)     ^ q7) << 4);
    const int cHi = (((2 * g + 1) ^ q7) << 4);

    // staging: thread T -> phys slot (row = T>>3, chunk = T&7); logical = (T&7)^((T>>3)&7)
    const int srow8 = T >> 3;
    const int sch   = (T & 7) ^ ((T >> 3) & 7);

    f32x4 acc[4][4];
#pragma unroll
    for (int i = 0; i < 4; ++i)
#pragma unroll
        for (int j = 0; j < 4; ++j)
            acc[i][j] = (f32x4){0.f, 0.f, 0.f, 0.f};

    const unsigned char* Asrc = Af8 + (size_t)(m_base + srow8) * DDIM + sch * 16;
    const unsigned char* Bsrc = Wf8 + (size_t)(n_base + srow8) * DDIM + sch * 16;
    const int wbyte = wave * 1024;

    // per gload: one wave stages 8 rows x 128 B. A = 4 blks (256 rows), B = 2 blks (128 rows)
    auto STAGE_A = [&](int kt, int blk) {
        gload_lds16(Asrc + (size_t)blk * 64 * DDIM + kt * 128,
                    &lds[(kt & 1) * 49152 + blk * 8192 + wbyte]);
    };
    auto STAGE_B = [&](int kt, int blk) {
        gload_lds16(Bsrc + (size_t)blk * 64 * DDIM + kt * 128,
                    &lds[(kt & 1) * 49152 + 32768 + blk * 8192 + wbyte]);
    };

    const int arow = wm * 64 + q;
    const int brow = wn * 64 + q;
    i32x8 bfr[4];   // B frags of current K-tile (read at phase 0, live 2 phases)

#define RD_FRAG(dst_, baseb_) { \
    const uint4 lo_ = *(const uint4*)&lds[(baseb_) + cLo]; \
    const uint4 hi_ = *(const uint4*)&lds[(baseb_) + cHi]; \
    dst_[0] = lo_.x; dst_[1] = lo_.y; dst_[2] = lo_.z; dst_[3] = lo_.w; \
    dst_[4] = hi_.x; dst_[5] = hi_.y; dst_[6] = hi_.z; dst_[7] = hi_.w; \
}

    // PH: one phase = mf rows {2j, 2j+1}, full K=128. 8 scale-MFMA.
#define PH(j, BB, STAGE_STMT, WAIT_STMT) { \
    i32x8 a0, a1; \
    RD_FRAG(a0, (BB) + (arow + (2*(j)    ) * 16) * 128); \
    RD_FRAG(a1, (BB) + (arow + (2*(j) + 1) * 16) * 128); \
    if ((j) == 0) { \
        _Pragma("unroll") \
        for (int nf = 0; nf < 4; ++nf) \
            RD_FRAG(bfr[nf], (BB) + 32768 + (brow + nf * 16) * 128); \
    } \
    STAGE_STMT; \
    if ((j) == 0) asm volatile("s_waitcnt lgkmcnt(8)" ::: "memory"); \
    asm volatile("s_barrier" ::: "memory"); \
    asm volatile("s_waitcnt lgkmcnt(0)" ::: "memory"); \
    __builtin_amdgcn_s_setprio(1); \
    _Pragma("unroll") \
    for (int nf = 0; nf < 4; ++nf) \
        acc[2*(j)][nf] = __builtin_amdgcn_mfma_scale_f32_16x16x128_f8f6f4( \
            a0, bfr[nf], acc[2*(j)][nf], 0, 0, 0, SCL8, 0, SCL8); \
    _Pragma("unroll") \
    for (int nf = 0; nf < 4; ++nf) \
        acc[2*(j)+1][nf] = __builtin_amdgcn_mfma_scale_f32_16x16x128_f8f6f4( \
            a1, bfr[nf], acc[2*(j)+1][nf], 0, 0, 0, SCL8, 0, SCL8); \
    __builtin_amdgcn_s_setprio(0); \
    WAIT_STMT; \
    asm volatile("s_barrier" ::: "memory"); \
}

    // ---- prologue: tile 0 fully staged ----
    STAGE_A(0, 0); STAGE_A(0, 1); STAGE_A(0, 2); STAGE_A(0, 3);
    STAGE_B(0, 0); STAGE_B(0, 1);
    asm volatile("s_waitcnt vmcnt(0)" ::: "memory");
    asm volatile("s_barrier" ::: "memory");

    // ---- main loop: 16 K-tiles (K=128 each) x 2 phases ----
    for (int t = 0; t < 16; ++t) {
        const int BB = (t & 1) * 49152;
        const bool st = (t < 15);
        PH(0, BB, { if (st) { STAGE_A(t + 1, 0); STAGE_A(t + 1, 1); STAGE_B(t + 1, 0); } }, {});
        PH(1, BB, { if (st) { STAGE_A(t + 1, 2); STAGE_A(t + 1, 3); STAGE_B(t + 1, 1); } },
                  { if (st) { asm volatile("s_waitcnt vmcnt(0)" ::: "memory"); } });
    }
#undef PH
#undef RD_FRAG

    // ---- epilogue: bias + exp + row-sum + target gather (16x16 C/D layout) ----
    const int grow_base = m_base + wm * 64;
    const int gcol_base = n_base + wn * 64;
#pragma unroll
    for (int mf = 0; mf < 4; ++mf) {
        const int rb = grow_base + mf * 16 + g * 4;
        int lbl[4];
#pragma unroll
        for (int r = 0; r < 4; ++r)
            lbl[r] = (rb + r < SROWS) ? labels[rb + r + 1] : -1;
        float rsum[4] = {0.f, 0.f, 0.f, 0.f};
#pragma unroll
        for (int nf = 0; nf < 4; ++nf) {
            const int gc = gcol_base + nf * 16 + q;
            const float bz = bias[gc];
            const f32x4 v = acc[mf][nf];
#pragma unroll
            for (int r = 0; r < 4; ++r) {
                const float s = v[r] + bz;
                if (lbl[r] == gc) atomicAdd(&tgt[rb + r], s);
                rsum[r] += __expf(s);
            }
        }
#pragma unroll
        for (int r = 0; r < 4; ++r) {
#pragma unroll
            for (int off = 1; off < 16; off <<= 1)
                rsum[r] += __shfl_xor(rsum[r], off);
        }
        if (q == 0) {
#pragma unroll
            for (int r = 0; r < 4; ++r)
                if (rb + r < SROWS) atomicAdd(&sumexp[rb + r], rsum[r]);
        }
    }
}

// ---------------- fallback: fp32 in, reg-staged cvt to bf16 (round-1 kernel) ----------------
__global__ __launch_bounds__(512, 2)
void ce_fused_gemm(const float* __restrict__ emb,
                   const float* __restrict__ W,
                   const float* __restrict__ bias,
                   const int* __restrict__ labels,
                   float* __restrict__ sumexp,
                   float* __restrict__ tgt)
{
    constexpr int BK = 64;
    constexpr int KT = 32;
    __shared__ __align__(16) unsigned short As[2][BM * BK];
    __shared__ __align__(16) unsigned short Bs[2][BN * BK];

    const int bid = blockIdx.x;
    const int L = (bid & 7) * (MT * NT / 8) + (bid >> 3);
    const int n_tile = L >> 3;
    const int m_tile = L & 7;
    const size_t m_base = (size_t)m_tile * BM;
    const size_t n_base = (size_t)n_tile * BN;

    const int tid  = threadIdx.x;
    const int lane = tid & 63;
    const int wave = tid >> 6;
    const int wm = wave >> 2;
    const int wn = wave & 3;
    const int q = lane & 15;
    const int g = lane >> 4;
    const int r0 = tid >> 3;
    const int kg = tid & 7;

    float4 stA[4][2], stB[4][2];
    f32x4 acc[8][4];
#pragma unroll
    for (int i = 0; i < 8; ++i)
#pragma unroll
        for (int j = 0; j < 4; ++j)
            acc[i][j] = (f32x4){0.f, 0.f, 0.f, 0.f};

    const float* Ab = emb + m_base * DDIM + (size_t)kg * 8;
    const float* Bb = W   + n_base * DDIM + (size_t)kg * 8;

#define STAGE_LOAD(kt_) { \
    const size_t ko = (size_t)(kt_) * BK; \
    _Pragma("unroll") \
    for (int p = 0; p < 4; ++p) { \
        const int row = r0 + p * 64; \
        const float4* pa = (const float4*)(Ab + (size_t)row * DDIM + ko); \
        stA[p][0] = pa[0]; stA[p][1] = pa[1]; \
        const float4* pb = (const float4*)(Bb + (size_t)row * DDIM + ko); \
        stB[p][0] = pb[0]; stB[p][1] = pb[1]; \
    } }

#define STAGE_WRITE(bf_) { \
    _Pragma("unroll") \
    for (int p = 0; p < 4; ++p) { \
        const int row = r0 + p * 64; \
        const int sw = (kg * 8) ^ ((row & 7) << 3); \
        uint4 ua; \
        ua.x = cvt_pk_bf16(stA[p][0].x, stA[p][0].y); \
        ua.y = cvt_pk_bf16(stA[p][0].z, stA[p][0].w); \
        ua.z = cvt_pk_bf16(stA[p][1].x, stA[p][1].y); \
        ua.w = cvt_pk_bf16(stA[p][1].z, stA[p][1].w); \
        *(uint4*)&As[bf_][row * BK + sw] = ua; \
        uint4 ub; \
        ub.x = cvt_pk_bf16(stB[p][0].x, stB[p][0].y); \
        ub.y = cvt_pk_bf16(stB[p][0].z, stB[p][0].w); \
        ub.z = cvt_pk_bf16(stB[p][1].x, stB[p][1].y); \
        ub.w = cvt_pk_bf16(stB[p][1].z, stB[p][1].w); \
        *(uint4*)&Bs[bf_][row * BK + sw] = ub; \
    } }

#define COMPUTE(bf_) { \
    _Pragma("unroll") \
    for (int kh = 0; kh < 2; ++kh) { \
        const int c = kh * 32 + g * 8; \
        bf16x8 bfr[4]; \
        _Pragma("unroll") \
        for (int nf = 0; nf < 4; ++nf) { \
            const int rr = wn * 64 + nf * 16 + q; \
            bfr[nf] = *(const bf16x8*)&Bs[bf_][rr * BK + (c ^ ((rr & 7) << 3))]; \
        } \
        _Pragma("unroll") \
        for (int mf = 0; mf < 8; ++mf) { \
            const int rr = wm * 128 + mf * 16 + q; \
            bf16x8 afr = *(const bf16x8*)&As[bf_][rr * BK + (c ^ ((rr & 7) << 3))]; \
            _Pragma("unroll") \
            for (int nf = 0; nf < 4; ++nf) \
                acc[mf][nf] = __builtin_amdgcn_mfma_f32_16x16x32_bf16(afr, bfr[nf], acc[mf][nf], 0, 0, 0); \
        } \
    } }

    STAGE_LOAD(0);
    STAGE_WRITE(0);
    __syncthreads();

    int buf = 0;
    for (int kt = 0; kt < KT; ++kt) {
        if (kt + 1 < KT) STAGE_LOAD(kt + 1);
        COMPUTE(buf);
        if (kt + 1 < KT) STAGE_WRITE(buf ^ 1);
        __syncthreads();
        buf ^= 1;
    }

    const int grow_base = (int)m_base + wm * 128;
    const int gcol_base = (int)n_base + wn * 64;
#pragma unroll
    for (int mf = 0; mf < 8; ++mf) {
        const int rb = grow_base + mf * 16 + g * 4;
        int lbl[4];
#pragma unroll
        for (int r = 0; r < 4; ++r)
            lbl[r] = (rb + r < SROWS) ? labels[rb + r + 1] : -1;
        float rsum[4] = {0.f, 0.f, 0.f, 0.f};
#pragma unroll
        for (int nf = 0; nf < 4; ++nf) {
            const int gc = gcol_base + nf * 16 + q;
            const float bz = bias[gc];
            const f32x4 v = acc[mf][nf];
#pragma unroll
            for (int r = 0; r < 4; ++r) {
                const float s = v[r] + bz;
                if (lbl[r] == gc) atomicAdd(&tgt[rb + r], s);
                rsum[r] += __expf(s);
            }
        }
#pragma unroll
        for (int r = 0; r < 4; ++r) {
#pragma unroll
            for (int off = 1; off < 16; off <<= 1)
                rsum[r] += __shfl_xor(rsum[r], off);
        }
        if (q == 0) {
#pragma unroll
            for (int r = 0; r < 4; ++r)
                if (rb + r < SROWS) atomicAdd(&sumexp[rb + r], rsum[r]);
        }
    }
#undef STAGE_LOAD
#undef STAGE_WRITE
#undef COMPUTE
}

__global__ void ce_finalize(const float* __restrict__ sumexp,
                            const float* __restrict__ tgt,
                            const int* __restrict__ labels,
                            float* __restrict__ out)
{
    const int tid = threadIdx.x;
    float acc = 0.f, cnt = 0.f;
    for (int s = tid; s < SROWS; s += 256) {
        if (labels[s + 1] != IGNORE_INDEX) {
            acc += __logf(sumexp[s]) - tgt[s];
            cnt += 1.f;
        }
    }
#pragma unroll
    for (int off = 32; off > 0; off >>= 1) {
        acc += __shfl_down(acc, off);
        cnt += __shfl_down(cnt, off);
    }
    __shared__ float sa[4], sc[4];
    if ((tid & 63) == 0) { sa[tid >> 6] = acc; sc[tid >> 6] = cnt; }
    __syncthreads();
    if (tid == 0) {
        float a = sa[0] + sa[1] + sa[2] + sa[3];
        float c = sc[0] + sc[1] + sc[2] + sc[3];
        out[0] = a / fmaxf(c, 1.f);
    }
}

extern "C" void kernel_launch(void* const* d_in, const int* in_sizes, int n_in,
                              void* d_out, int out_size, void* d_ws, size_t ws_size,
                              hipStream_t stream)
{
    const float* emb    = (const float*)d_in[1];
    const float* W      = (const float*)d_in[2];
    const float* bias   = (const float*)d_in[3];
    const int*   labels = (const int*)d_in[4];

    float* wsf    = (float*)d_ws;
    float* sumexp = wsf;
    float* tgt    = wsf + 2048;

    hipMemsetAsync(d_ws, 0, WS_ACC_BYTES, stream);

    if (ws_size >= WS_NEED8) {
        unsigned char* Af8 = (unsigned char*)d_ws + WS_ACC_BYTES;
        unsigned char* Wf8 = (unsigned char*)d_ws + WS_ACC_BYTES + WS_A8_BYTES;
        cvt_f32_fp8<<<dim3(4096), dim3(256), 0, stream>>>(W, (unsigned*)Wf8, (size_t)128000 * 2048 / 4);
        cvt_f32_fp8<<<dim3(512),  dim3(256), 0, stream>>>(emb, (unsigned*)Af8, (size_t)2048 * 2048 / 4);
        ce_gemmf8b<<<dim3(8000), dim3(512), 0, stream>>>(Af8, Wf8, bias, labels, sumexp, tgt);
    } else {
        ce_fused_gemm<<<dim3(MT * NT), dim3(512), 0, stream>>>(emb, W, bias, labels, sumexp, tgt);
    }
    ce_finalize<<<dim3(1), dim3(256), 0, stream>>>(sumexp, tgt, labels, (float*)d_out);
}

// Round 11
// 1116.099 us; speedup vs baseline: 1.5371x; 1.0760x over previous
//
#include <hip/hip_runtime.h>
#include <hip/hip_bf16.h>

#define IGNORE_INDEX (-100)

using f32x4  = __attribute__((ext_vector_type(4))) float;
using bf16x8 = __attribute__((ext_vector_type(8))) short;
using i32x8  = __attribute__((ext_vector_type(8))) int;

constexpr int BM = 256, BN = 256;
constexpr int MT = 8;      // m tiles (2048 / 256)
constexpr int NT = 500;    // fallback n tiles (128000 / 256)
constexpr int SROWS = 2047;
constexpr int DDIM = 2048;

// fp8 workspace layout
constexpr size_t WS_ACC_BYTES = 16384;
constexpr size_t WS_A8_BYTES  = (size_t)2048 * 2048;
constexpr size_t WS_W8_BYTES  = (size_t)128000 * 2048;
constexpr size_t WS_NEED8     = WS_ACC_BYTES + WS_A8_BYTES + WS_W8_BYTES;

#define SCL8 0x7F7F7F7F   // E8M0 = 127 -> 2^0 = 1.0 in all four bytes

__device__ __forceinline__ unsigned cvt_pk_bf16(float lo, float hi) {
    unsigned r;
    asm("v_cvt_pk_bf16_f32 %0, %1, %2" : "=v"(r) : "v"(lo), "v"(hi));
    return r;
}

__device__ __forceinline__ void gload_lds16(const void* g, void* l) {
    __builtin_amdgcn_global_load_lds(
        (__attribute__((address_space(1))) void*)(g),
        (__attribute__((address_space(3))) void*)(l), 16, 0, 0);
}

// ---------------- prepass: fp32 -> fp8 e4m3 (HW cvt, 4 floats/thread) ----------------
__global__ __launch_bounds__(256)
void cvt_f32_fp8(const float* __restrict__ src, unsigned* __restrict__ dst, size_t n4)
{
    size_t i = (size_t)blockIdx.x * 256 + threadIdx.x;
    const size_t stride = (size_t)gridDim.x * 256;
    for (; i < n4; i += stride) {
        const float4 v = ((const float4*)src)[i];
        unsigned u = __builtin_amdgcn_cvt_pk_fp8_f32(v.x, v.y, 0, false);
        u = __builtin_amdgcn_cvt_pk_fp8_f32(v.z, v.w, u, true);
        dst[i] = u;
    }
}

// ---- main fused GEMM + CE: MX-fp8 K=128, 256x128 tile, 3-buf counted-vmcnt cadence ----
__global__ __launch_bounds__(512, 2)
void ce_gemmf8c(const unsigned char* __restrict__ Af8,
                const unsigned char* __restrict__ Wf8,
                const float* __restrict__ bias,
                const int* __restrict__ labels,
                float* __restrict__ sumexp,
                float* __restrict__ tgt)
{
    // 3 bufs x (A[256][128B] = 32KB + B[128][128B] = 16KB) = 144 KiB
    __shared__ __align__(16) unsigned char lds[3 * 49152];

    const int bid = blockIdx.x;                  // 8000 blocks, %8==0 -> bijective
    const int L = (bid & 7) * 1000 + (bid >> 3);
    const int n_tile = L >> 3;                   // 0..999
    const int m_tile = L & 7;                    // 0..7
    const int m_base = m_tile * BM;
    const int n_base = n_tile * 128;

    const int T    = threadIdx.x;
    const int lane = T & 63;
    const int wave = T >> 6;
    const int wm = wave >> 1;   // 0..3 (64-row group)
    const int wn = wave & 1;    // 0..1 (64-col group)
    const int q = lane & 15;
    const int g = lane >> 4;    // 0..3
    const int q7 = q & 7;
    // lane's 32 K-bytes = logical 16B-chunks {2g, 2g+1}; phys = logical ^ (row&7), row&7 == q7
    const int cLo = (((2 * g)     ^ q7) << 4);
    const int cHi = (((2 * g + 1) ^ q7) << 4);

    // staging: thread T -> phys slot (row = T>>3, chunk = T&7); logical = (T&7)^((T>>3)&7)
    const int srow8 = T >> 3;
    const int sch   = (T & 7) ^ ((T >> 3) & 7);

    f32x4 acc[4][4];
#pragma unroll
    for (int i = 0; i < 4; ++i)
#pragma unroll
        for (int j = 0; j < 4; ++j)
            acc[i][j] = (f32x4){0.f, 0.f, 0.f, 0.f};

    const unsigned char* Asrc = Af8 + (size_t)(m_base + srow8) * DDIM + sch * 16;
    const unsigned char* Bsrc = Wf8 + (size_t)(n_base + srow8) * DDIM + sch * 16;
    const int wbyte = wave * 1024;

    // per gload: one wave stages 8 rows x 128 B. A = 4 blks (256 rows), B = 2 blks (128 rows)
    auto STAGE_A = [&](int kt, int blk, int buf) {
        gload_lds16(Asrc + (size_t)blk * 64 * DDIM + kt * 128,
                    &lds[buf * 49152 + blk * 8192 + wbyte]);
    };
    auto STAGE_B = [&](int kt, int blk, int buf) {
        gload_lds16(Bsrc + (size_t)blk * 64 * DDIM + kt * 128,
                    &lds[buf * 49152 + 32768 + blk * 8192 + wbyte]);
    };

    const int arow = wm * 64 + q;
    const int brow = wn * 64 + q;
    i32x8 bfr[4];   // B frags of current K-tile (read at phase 0, live 2 phases)

#define RD_FRAG(dst_, baseb_) { \
    const uint4 lo_ = *(const uint4*)&lds[(baseb_) + cLo]; \
    const uint4 hi_ = *(const uint4*)&lds[(baseb_) + cHi]; \
    dst_[0] = lo_.x; dst_[1] = lo_.y; dst_[2] = lo_.z; dst_[3] = lo_.w; \
    dst_[4] = hi_.x; dst_[5] = hi_.y; dst_[6] = hi_.z; dst_[7] = hi_.w; \
}

    // PH: one phase = mf rows {2j, 2j+1}, full K=128. 8 scale-MFMA.
#define PH(j, BB, STAGE_STMT, WAIT_STMT) { \
    i32x8 a0, a1; \
    RD_FRAG(a0, (BB) + (arow + (2*(j)    ) * 16) * 128); \
    RD_FRAG(a1, (BB) + (arow + (2*(j) + 1) * 16) * 128); \
    if ((j) == 0) { \
        _Pragma("unroll") \
        for (int nf = 0; nf < 4; ++nf) \
            RD_FRAG(bfr[nf], (BB) + 32768 + (brow + nf * 16) * 128); \
    } \
    STAGE_STMT; \
    if ((j) == 0) asm volatile("s_waitcnt lgkmcnt(8)" ::: "memory"); \
    asm volatile("s_barrier" ::: "memory"); \
    asm volatile("s_waitcnt lgkmcnt(0)" ::: "memory"); \
    __builtin_amdgcn_s_setprio(1); \
    _Pragma("unroll") \
    for (int nf = 0; nf < 4; ++nf) \
        acc[2*(j)][nf] = __builtin_amdgcn_mfma_scale_f32_16x16x128_f8f6f4( \
            a0, bfr[nf], acc[2*(j)][nf], 0, 0, 0, SCL8, 0, SCL8); \
    _Pragma("unroll") \
    for (int nf = 0; nf < 4; ++nf) \
        acc[2*(j)+1][nf] = __builtin_amdgcn_mfma_scale_f32_16x16x128_f8f6f4( \
            a1, bfr[nf], acc[2*(j)+1][nf], 0, 0, 0, SCL8, 0, SCL8); \
    __builtin_amdgcn_s_setprio(0); \
    WAIT_STMT; \
    asm volatile("s_barrier" ::: "memory"); \
}

    // ---- prologue: tiles 0 and 1 fully staged (buf 0, buf 1) ----
    STAGE_A(0, 0, 0); STAGE_A(0, 1, 0); STAGE_A(0, 2, 0); STAGE_A(0, 3, 0);
    STAGE_B(0, 0, 0); STAGE_B(0, 1, 0);
    STAGE_A(1, 0, 1); STAGE_A(1, 1, 1); STAGE_A(1, 2, 1); STAGE_A(1, 3, 1);
    STAGE_B(1, 0, 1); STAGE_B(1, 1, 1);
    asm volatile("s_waitcnt vmcnt(6)" ::: "memory");   // tile 0 landed, tile 1 in flight
    asm volatile("s_barrier" ::: "memory");

    // ---- main loop: 16 K-tiles (K=128 each) x 2 phases; stage t+2, counted vmcnt ----
    int cb = 0, sb = 2;
    for (int t = 0; t < 16; ++t) {
        const int BB = cb * 49152;
        const bool st = (t < 14);
        PH(0, BB, { if (st) { STAGE_A(t + 2, 0, sb); STAGE_A(t + 2, 1, sb); STAGE_B(t + 2, 0, sb); } }, {});
        PH(1, BB, { if (st) { STAGE_A(t + 2, 2, sb); STAGE_A(t + 2, 3, sb); STAGE_B(t + 2, 1, sb); } },
                  { if (st)          { asm volatile("s_waitcnt vmcnt(6)" ::: "memory"); }
                    else if (t == 14){ asm volatile("s_waitcnt vmcnt(0)" ::: "memory"); } });
        cb = (cb == 2) ? 0 : cb + 1;
        sb = (sb == 2) ? 0 : sb + 1;
    }
#undef PH
#undef RD_FRAG

    // ---- epilogue: bias + exp + row-sum + target gather (16x16 C/D layout) ----
    const int grow_base = m_base + wm * 64;
    const int gcol_base = n_base + wn * 64;
#pragma unroll
    for (int mf = 0; mf < 4; ++mf) {
        const int rb = grow_base + mf * 16 + g * 4;
        int lbl[4];
#pragma unroll
        for (int r = 0; r < 4; ++r)
            lbl[r] = (rb + r < SROWS) ? labels[rb + r + 1] : -1;
        float rsum[4] = {0.f, 0.f, 0.f, 0.f};
#pragma unroll
        for (int nf = 0; nf < 4; ++nf) {
            const int gc = gcol_base + nf * 16 + q;
            const float bz = bias[gc];
            const f32x4 v = acc[mf][nf];
#pragma unroll
            for (int r = 0; r < 4; ++r) {
                const float s = v[r] + bz;
                if (lbl[r] == gc) atomicAdd(&tgt[rb + r], s);
                rsum[r] += __expf(s);
            }
        }
#pragma unroll
        for (int r = 0; r < 4; ++r) {
#pragma unroll
            for (int off = 1; off < 16; off <<= 1)
                rsum[r] += __shfl_xor(rsum[r], off);
        }
        if (q == 0) {
#pragma unroll
            for (int r = 0; r < 4; ++r)
                if (rb + r < SROWS) atomicAdd(&sumexp[rb + r], rsum[r]);
        }
    }
}

// ---------------- fallback: fp32 in, reg-staged cvt to bf16 (round-1 kernel) ----------------
__global__ __launch_bounds__(512, 2)
void ce_fused_gemm(const float* __restrict__ emb,
                   const float* __restrict__ W,
                   const float* __restrict__ bias,
                   const int* __restrict__ labels,
                   float* __restrict__ sumexp,
                   float* __restrict__ tgt)
{
    constexpr int BK = 64;
    constexpr int KT = 32;
    __shared__ __align__(16) unsigned short As[2][BM * BK];
    __shared__ __align__(16) unsigned short Bs[2][BN * BK];

    const int bid = blockIdx.x;
    const int L = (bid & 7) * (MT * NT / 8) + (bid >> 3);
    const int n_tile = L >> 3;
    const int m_tile = L & 7;
    const size_t m_base = (size_t)m_tile * BM;
    const size_t n_base = (size_t)n_tile * BN;

    const int tid  = threadIdx.x;
    const int lane = tid & 63;
    const int wave = tid >> 6;
    const int wm = wave >> 2;
    const int wn = wave & 3;
    const int q = lane & 15;
    const int g = lane >> 4;
    const int r0 = tid >> 3;
    const int kg = tid & 7;

    float4 stA[4][2], stB[4][2];
    f32x4 acc[8][4];
#pragma unroll
    for (int i = 0; i < 8; ++i)
#pragma unroll
        for (int j = 0; j < 4; ++j)
            acc[i][j] = (f32x4){0.f, 0.f, 0.f, 0.f};

    const float* Ab = emb + m_base * DDIM + (size_t)kg * 8;
    const float* Bb = W   + n_base * DDIM + (size_t)kg * 8;

#define STAGE_LOAD(kt_) { \
    const size_t ko = (size_t)(kt_) * BK; \
    _Pragma("unroll") \
    for (int p = 0; p < 4; ++p) { \
        const int row = r0 + p * 64; \
        const float4* pa = (const float4*)(Ab + (size_t)row * DDIM + ko); \
        stA[p][0] = pa[0]; stA[p][1] = pa[1]; \
        const float4* pb = (const float4*)(Bb + (size_t)row * DDIM + ko); \
        stB[p][0] = pb[0]; stB[p][1] = pb[1]; \
    } }

#define STAGE_WRITE(bf_) { \
    _Pragma("unroll") \
    for (int p = 0; p < 4; ++p) { \
        const int row = r0 + p * 64; \
        const int sw = (kg * 8) ^ ((row & 7) << 3); \
        uint4 ua; \
        ua.x = cvt_pk_bf16(stA[p][0].x, stA[p][0].y); \
        ua.y = cvt_pk_bf16(stA[p][0].z, stA[p][0].w); \
        ua.z = cvt_pk_bf16(stA[p][1].x, stA[p][1].y); \
        ua.w = cvt_pk_bf16(stA[p][1].z, stA[p][1].w); \
        *(uint4*)&As[bf_][row * BK + sw] = ua; \
        uint4 ub; \
        ub.x = cvt_pk_bf16(stB[p][0].x, stB[p][0].y); \
        ub.y = cvt_pk_bf16(stB[p][0].z, stB[p][0].w); \
        ub.z = cvt_pk_bf16(stB[p][1].x, stB[p][1].y); \
        ub.w = cvt_pk_bf16(stB[p][1].z, stB[p][1].w); \
        *(uint4*)&Bs[bf_][row * BK + sw] = ub; \
    } }

#define COMPUTE(bf_) { \
    _Pragma("unroll") \
    for (int kh = 0; kh < 2; ++kh) { \
        const int c = kh * 32 + g * 8; \
        bf16x8 bfr[4]; \
        _Pragma("unroll") \
        for (int nf = 0; nf < 4; ++nf) { \
            const int rr = wn * 64 + nf * 16 + q; \
            bfr[nf] = *(const bf16x8*)&Bs[bf_][rr * BK + (c ^ ((rr & 7) << 3))]; \
        } \
        _Pragma("unroll") \
        for (int mf = 0; mf < 8; ++mf) { \
            const int rr = wm * 128 + mf * 16 + q; \
            bf16x8 afr = *(const bf16x8*)&As[bf_][rr * BK + (c ^ ((rr & 7) << 3))]; \
            _Pragma("unroll") \
            for (int nf = 0; nf < 4; ++nf) \
                acc[mf][nf] = __builtin_amdgcn_mfma_f32_16x16x32_bf16(afr, bfr[nf], acc[mf][nf], 0, 0, 0); \
        } \
    } }

    STAGE_LOAD(0);
    STAGE_WRITE(0);
    __syncthreads();

    int buf = 0;
    for (int kt = 0; kt < KT; ++kt) {
        if (kt + 1 < KT) STAGE_LOAD(kt + 1);
        COMPUTE(buf);
        if (kt + 1 < KT) STAGE_WRITE(buf ^ 1);
        __syncthreads();
        buf ^= 1;
    }

    const int grow_base = (int)m_base + wm * 128;
    const int gcol_base = (int)n_base + wn * 64;
#pragma unroll
    for (int mf = 0; mf < 8; ++mf) {
        const int rb = grow_base + mf * 16 + g * 4;
        int lbl[4];
#pragma unroll
        for (int r = 0; r < 4; ++r)
            lbl[r] = (rb + r < SROWS) ? labels[rb + r + 1] : -1;
        float rsum[4] = {0.f, 0.f, 0.f, 0.f};
#pragma unroll
        for (int nf = 0; nf < 4; ++nf) {
            const int gc = gcol_base + nf * 16 + q;
            const float bz = bias[gc];
            const f32x4 v = acc[mf][nf];
#pragma unroll
            for (int r = 0; r < 4; ++r) {
                const float s = v[r] + bz;
                if (lbl[r] == gc) atomicAdd(&tgt[rb + r], s);
                rsum[r] += __expf(s);
            }
        }
#pragma unroll
        for (int r = 0; r < 4; ++r) {
#pragma unroll
            for (int off = 1; off < 16; off <<= 1)
                rsum[r] += __shfl_xor(rsum[r], off);
        }
        if (q == 0) {
#pragma unroll
            for (int r = 0; r < 4; ++r)
                if (rb + r < SROWS) atomicAdd(&sumexp[rb + r], rsum[r]);
        }
    }
#undef STAGE_LOAD
#undef STAGE_WRITE
#undef COMPUTE
}

__global__ void ce_finalize(const float* __restrict__ sumexp,
                            const float* __restrict__ tgt,
                            const int* __restrict__ labels,
                            float* __restrict__ out)
{
    const int tid = threadIdx.x;
    float acc = 0.f, cnt = 0.f;
    for (int s = tid; s < SROWS; s += 256) {
        if (labels[s + 1] != IGNORE_INDEX) {
            acc += __logf(sumexp[s]) - tgt[s];
            cnt += 1.f;
        }
    }
#pragma unroll
    for (int off = 32; off > 0; off >>= 1) {
        acc += __shfl_down(acc, off);
        cnt += __shfl_down(cnt, off);
    }
    __shared__ float sa[4], sc[4];
    if ((tid & 63) == 0) { sa[tid >> 6] = acc; sc[tid >> 6] = cnt; }
    __syncthreads();
    if (tid == 0) {
        float a = sa[0] + sa[1] + sa[2] + sa[3];
        float c = sc[0] + sc[1] + sc[2] + sc[3];
        out[0] = a / fmaxf(c, 1.f);
    }
}

extern "C" void kernel_launch(void* const* d_in, const int* in_sizes, int n_in,
                              void* d_out, int out_size, void* d_ws, size_t ws_size,
                              hipStream_t stream)
{
    const float* emb    = (const float*)d_in[1];
    const float* W      = (const float*)d_in[2];
    const float* bias   = (const float*)d_in[3];
    const int*   labels = (const int*)d_in[4];

    float* wsf    = (float*)d_ws;
    float* sumexp = wsf;
    float* tgt    = wsf + 2048;

    hipMemsetAsync(d_ws, 0, WS_ACC_BYTES, stream);

    if (ws_size >= WS_NEED8) {
        unsigned char* Af8 = (unsigned char*)d_ws + WS_ACC_BYTES;
        unsigned char* Wf8 = (unsigned char*)d_ws + WS_ACC_BYTES + WS_A8_BYTES;
        cvt_f32_fp8<<<dim3(4096), dim3(256), 0, stream>>>(W, (unsigned*)Wf8, (size_t)128000 * 2048 / 4);
        cvt_f32_fp8<<<dim3(512),  dim3(256), 0, stream>>>(emb, (unsigned*)Af8, (size_t)2048 * 2048 / 4);
        ce_gemmf8c<<<dim3(8000), dim3(512), 0, stream>>>(Af8, Wf8, bias, labels, sumexp, tgt);
    } else {
        ce_fused_gemm<<<dim3(MT * NT), dim3(512), 0, stream>>>(emb, W, bias, labels, sumexp, tgt);
    }
    ce_finalize<<<dim3(1), dim3(256), 0, stream>>>(sumexp, tgt, labels, (float*)d_out);
}